// Round 1
// 1493.604 us; speedup vs baseline: 1.0319x; 1.0319x over previous
//
#include <hip/hip_runtime.h>
#include <hip/hip_bf16.h>
#include <stdint.h>

typedef __hip_bfloat16 bf16;
typedef __attribute__((ext_vector_type(8))) __bf16 bf16x8;
typedef __attribute__((ext_vector_type(4))) float f32x4;
typedef __attribute__((ext_vector_type(4))) int i32x4;

#define GN_EPS 1e-5f

__device__ __forceinline__ float silu_f(float x) {
  return x / (1.f + __expf(-x));
}

// dtype-dual scalar load: flag==1 -> f32 data, flag==0 -> bf16 data
__device__ __forceinline__ float ldf(const void* p, size_t i, int f) {
  return f ? ((const float*)p)[i]
           : __bfloat162float(((const bf16*)p)[i]);
}

// async global->LDS, 16B per lane. LDS dest is wave-uniform base (+lane*16 HW).
__device__ __forceinline__ void llds16(const void* g, void* l) {
  __builtin_amdgcn_global_load_lds(
      (const __attribute__((address_space(1))) unsigned int*)g,
      (__attribute__((address_space(3))) unsigned int*)l, 16, 0, 0);
}

// ---------------- dtype detect: scan gn1_w as bf16 halves -------------------
__global__ void detect_k(const void* __restrict__ gn1w, int* __restrict__ flag) {
  if (threadIdx.x == 0 && blockIdx.x == 0) {
    const unsigned short* u = (const unsigned short*)gn1w;
    float mx = 0.f;
    for (int i = 0; i < 128; ++i) {
      unsigned int b = ((unsigned int)u[i]) << 16;
      float v = __uint_as_float(b);
      v = fabsf(v);
      if (!isnan(v) && v > mx) mx = v;
    }
    flag[0] = (mx > 1e4f) ? 1 : 0;
  }
}

// ---------------- transpose (K, CI, CO) -> (K, CO, CI), out bf16 ------------
__global__ void transpose_k(const void* __restrict__ in, bf16* __restrict__ out,
                            int CI, int CO, const int* __restrict__ flagp) {
  const int f = *flagp;
  int k = blockIdx.y;
  int ntco = CO >> 5;
  int tci = blockIdx.x / ntco, tco = blockIdx.x % ntco;
  __shared__ float t[32][33];
  int tx = threadIdx.x & 31, ty = threadIdx.x >> 5;
  size_t base = (size_t)k * CI * CO;
  bf16* dst = out + base;
#pragma unroll
  for (int j = 0; j < 4; ++j)
    t[ty + 8 * j][tx] =
        ldf(in, base + (size_t)(tci * 32 + ty + 8 * j) * CO + tco * 32 + tx, f);
  __syncthreads();
#pragma unroll
  for (int j = 0; j < 4; ++j)
    dst[(size_t)(tco * 32 + ty + 8 * j) * CI + tci * 32 + tx] =
        __float2bfloat16(t[tx][ty + 8 * j]);
}

// ---------------- group-norm stats: sum/sumsq per group ----
__global__ void gn_stats_k(const void* __restrict__ x, float* __restrict__ raw,
                           int rows, int C, const int* __restrict__ flagp) {
  const int f = *flagp;
  int tid = threadIdx.x;
  int rpb = 256 / C;
  int c = tid & (C - 1);
  int stripe = tid / C;
  float s = 0.f, sq = 0.f;
  for (int r = blockIdx.x * rpb + stripe; r < rows; r += gridDim.x * rpb) {
    float v = ldf(x, (size_t)r * C + c, f);
    s += v; sq += v * v;
  }
  __shared__ float ls[256], lq[256];
  ls[tid] = s; lq[tid] = sq;
  __syncthreads();
  if (tid < 32) {
    int per = C >> 5;
    float as = 0.f, aq = 0.f;
    for (int st = 0; st < rpb; ++st)
      for (int e = 0; e < per; ++e) {
        int idx = st * C + tid * per + e;
        as += ls[idx]; aq += lq[idx];
      }
    atomicAdd(&raw[tid], as);
    atomicAdd(&raw[32 + tid], aq);
  }
}

__global__ void gn_fin_k(const float* __restrict__ raw, float* __restrict__ fin,
                         float count) {
  int g = threadIdx.x;
  if (g < 32) {
    float mu = raw[g] / count;
    float var = fmaxf(raw[32 + g] / count - mu * mu, 0.f);
    fin[g] = mu;
    fin[32 + g] = rsqrtf(var + GN_EPS);
  }
}

// ---------------- build per-cell voxel slots (<=8 parents per 2x cell) ------
__global__ void slots_k(const int* __restrict__ seg, int* __restrict__ cnt,
                        int* __restrict__ slots, int N) {
  int i = blockIdx.x * 256 + threadIdx.x;
  if (i >= N) return;
  int s = seg[i];
  int p = atomicAdd(&cnt[s], 1);
  if (p < 8) slots[s * 8 + p] = i;
}

// ---------------- downsample: x_d = mean(f), h_d = mean(silu(gn1(f))) -------
__global__ void down_k(const void* __restrict__ feats, const int* __restrict__ slots,
                       const int* __restrict__ cnt, const float* __restrict__ fin1,
                       const void* __restrict__ gw, const void* __restrict__ gb,
                       bf16* __restrict__ xd, bf16* __restrict__ hd, int M,
                       const int* __restrict__ flagp) {
  const int f = *flagp;
  int cell = blockIdx.x * 2 + (threadIdx.x >> 7);
  int c = threadIdx.x & 127;
  if (cell >= M) return;
  int n = min(cnt[cell], 8);
  int g = c >> 2;
  float mu = fin1[g], is = fin1[32 + g];
  float w = ldf(gw, c, f), b = ldf(gb, c, f);
  float xs = 0.f, hs = 0.f;
  for (int j = 0; j < n; ++j) {
    int v = slots[cell * 8 + j];
    float fv = ldf(feats, (size_t)v * 128 + c, f);
    xs += fv;
    hs += silu_f((fv - mu) * is * w + b);
  }
  float inv = 1.f / (float)max(n, 1);
  xd[(size_t)cell * 128 + c] = __float2bfloat16(xs * inv);
  hd[(size_t)cell * 128 + c] = __float2bfloat16(hs * inv);
}

// ---------------- h2 = silu(gn2(h1)) in-place, vectorized bf16x8 ------------
__global__ void act2_k(bf16* __restrict__ h, const float* __restrict__ fin2,
                       const void* __restrict__ gw, const void* __restrict__ gb,
                       size_t total8, const int* __restrict__ flagp) {
  const int f = *flagp;
  size_t i = (size_t)blockIdx.x * 256 + threadIdx.x;
  if (i >= total8) return;
  int c0 = (int)((i * 8) & 255);       // 8 consecutive channels, same group
  int g = c0 >> 3;
  float mu = fin2[g], is = fin2[32 + g];
  bf16x8 v = *reinterpret_cast<bf16x8*>(h + i * 8);
  bf16x8 o;
#pragma unroll
  for (int j = 0; j < 8; ++j) {
    float x = (float)v[j];
    float t = (x - mu) * is * ldf(gw, c0 + j, f) + ldf(gb, c0 + j, f);
    o[j] = (__bf16)silu_f(t);
  }
  *reinterpret_cast<bf16x8*>(h + i * 8) = o;
}

// ---------------- gather-GEMM conv, v2 ---------------------------------------
// BK=64 (128B LDS rows), XOR-swizzled chunks (c ^= row&7), global_load_lds
// staging with pre-swizzled global source, double-buffered LDS, one raw
// barrier per K-tile with prefetch in flight, XCD-aware block swizzle.
// Wt layout: [k][cout][cin]; if SKIP, 28th block at Wt + 27*256*CIN with
// layout [cout][128] fed by Xd (src = self). Missing neighbors -> zero page.
template <int CIN, bool SKIP>
__global__ __launch_bounds__(256, 2) void conv_k(
    const bf16* __restrict__ A, const bf16* __restrict__ Wt,
    const void* __restrict__ bias, const void* __restrict__ bias2,
    const bf16* __restrict__ Xd, const int* __restrict__ nbr,
    void* __restrict__ out, int M, int nwg, const void* __restrict__ zp,
    const int* __restrict__ biasflagp, const int* __restrict__ outflagp) {
  constexpr int NCB = CIN / 64;                 // K-tiles per neighbor
  constexpr int NT = 27 * NCB + (SKIP ? 2 : 0); // total K-tiles
  __shared__ alignas(16) char smem[2 * 32768];  // 2 bufs x (A 16K + B 16K)

  const int bflag = *biasflagp, oflag = *outflagp;
  const int tid = threadIdx.x;
  const int wave = tid >> 6, lane = tid & 63;

  // --- XCD-aware bijective block swizzle (m204) ---
  int bid = blockIdx.x;
  int q = nwg >> 3, r8 = nwg & 7, xcd = bid & 7, ix = bid >> 3;
  int wg = (xcd < r8 ? xcd * (q + 1) : r8 * (q + 1) + (xcd - r8) * q) + ix;
  const int row0 = (wg >> 1) * 128, n0 = (wg & 1) * 128;

  // staging geometry: row = ro*32 + wave*8 + rb8, slot = lane&7
  const int rb8 = lane >> 3;          // 0..7 (== row&7)
  const int slot = lane & 7;
  const int gc = slot ^ rb8;          // pre-swizzled source chunk (m173)
  // fragment geometry
  const int mrow = lane & 15, quad = lane >> 4;
  const int wr = wave >> 1, wc = wave & 1;

  auto nbr_fetch = [&](int t) -> i32x4 {
    i32x4 s;
    bool isW = (!SKIP) || (t < 27 * NCB);
    int kk = isW ? (t / NCB) : 0;
#pragma unroll
    for (int ro = 0; ro < 4; ++ro) {
      int g = row0 + ro * 32 + wave * 8 + rb8;
      int v = -1;
      if (isW) {
        if (g < M) v = nbr[(size_t)g * 27 + kk];
      } else {
        if (g < M) v = g;
      }
      s[ro] = v;
    }
    return s;
  };

  auto stage = [&](int t, char* buf, i32x4 srcs) {
    bool isW = (!SKIP) || (t < 27 * NCB);
    int cb = isW ? (t % NCB) : (t - 27 * NCB);
    int cink = isW ? CIN : 128;
    const bf16* Ab = isW ? A : Xd;
    const bf16* Wb = Wt + (isW ? (size_t)(t / NCB) * (256 * CIN)
                               : (size_t)27 * (256 * CIN));
    const int coff = cb * 64 + gc * 8;   // elements
#pragma unroll
    for (int ro = 0; ro < 4; ++ro) {
      int rrow = ro * 32 + wave * 8 + rb8;
      int src = srcs[ro];
      const bf16* ga = (src >= 0) ? Ab + (size_t)src * cink + coff
                                  : (const bf16*)zp;
      const bf16* gw2 = Wb + (size_t)(n0 + rrow) * cink + coff;
      char* la = buf + ro * 4096 + wave * 1024;           // +lane*16 implicit
      char* lb = buf + 16384 + ro * 4096 + wave * 1024;
      llds16(ga, la);
      llds16(gw2, lb);
    }
  };

  f32x4 acc[4][4] = {};

  // prologue: stage tile 0, prefetch nbr for tile 1
  i32x4 sN = nbr_fetch(0);
  stage(0, smem, sN);
  sN = nbr_fetch(1);
  asm volatile("s_waitcnt vmcnt(0)" ::: "memory");
  __builtin_amdgcn_s_barrier();

#pragma unroll 2
  for (int t = 0; t < NT; ++t) {
    char* cur = smem + (t & 1) * 32768;
    if (t + 1 < NT) stage(t + 1, smem + ((t + 1) & 1) * 32768, sN);
    if (t + 2 < NT) sN = nbr_fetch(t + 2);
    const char* sA = cur + (size_t)(wr * 64 + mrow) * 128;
    const char* sB = cur + 16384 + (size_t)(wc * 64 + mrow) * 128;
#pragma unroll
    for (int ks = 0; ks < 2; ++ks) {
      const int co = ((ks * 4 + quad) ^ (mrow & 7)) * 16;  // swizzled read
      bf16x8 af[4], bv[4];
#pragma unroll
      for (int i = 0; i < 4; ++i)
        af[i] = *reinterpret_cast<const bf16x8*>(sA + i * (16 * 128) + co);
#pragma unroll
      for (int j = 0; j < 4; ++j)
        bv[j] = *reinterpret_cast<const bf16x8*>(sB + j * (16 * 128) + co);
      __builtin_amdgcn_s_setprio(1);
#pragma unroll
      for (int i = 0; i < 4; ++i)
#pragma unroll
        for (int j = 0; j < 4; ++j)
          acc[i][j] = __builtin_amdgcn_mfma_f32_16x16x32_bf16(af[i], bv[j],
                                                              acc[i][j], 0, 0, 0);
      __builtin_amdgcn_s_setprio(0);
    }
    // next tile's loads must have landed before anyone reads the other buffer
    asm volatile("s_waitcnt vmcnt(0)" ::: "memory");
    __builtin_amdgcn_s_barrier();
  }

  // ---- epilogue: bias (+bias2), store. C/D: col=lane&15, row=quad*4+r ------
#pragma unroll
  for (int j = 0; j < 4; ++j) {
    int col = n0 + wc * 64 + j * 16 + mrow;
    float bvl = ldf(bias, col, bflag);
    if (SKIP) bvl += ldf(bias2, col, bflag);
#pragma unroll
    for (int i = 0; i < 4; ++i) {
      int rb = row0 + wr * 64 + i * 16 + quad * 4;
#pragma unroll
      for (int r = 0; r < 4; ++r) {
        int row = rb + r;
        if (row < M) {
          size_t idx = (size_t)row * 256 + col;
          float val = acc[i][j][r] + bvl;
          if (oflag) ((float*)out)[idx] = val;
          else ((bf16*)out)[idx] = __float2bfloat16(val);
        }
      }
    }
  }
}

extern "C" void kernel_launch(void* const* d_in, const int* in_sizes, int n_in,
                              void* d_out, int out_size, void* d_ws, size_t ws_size,
                              hipStream_t stream) {
  const void* feats = d_in[0];
  const void* gn1w = d_in[1];
  const void* gn1b = d_in[2];
  const void* W1 = d_in[3];
  const void* b1 = d_in[4];
  const void* gn2w = d_in[5];
  const void* gn2b = d_in[6];
  const void* W2 = d_in[7];
  const void* b2 = d_in[8];
  const void* Wsk = d_in[9];
  const void* bsk = d_in[10];
  const int* pool = (const int*)d_in[11];
  const int* nbr = (const int*)d_in[12];
  const int N = in_sizes[0] / 128;
  const int M = out_size / 256;

  char* ws = (char*)d_ws;
  auto aup = [](size_t x) { return (x + 255) & ~(size_t)255; };
  float* raw1 = (float*)(ws + 0);      // 64 f32
  float* raw2 = (float*)(ws + 256);    // 64 f32
  int* flag = (int*)(ws + 512);        // dtype flag (1 = f32 inputs)
  int* zeroflag = (int*)(ws + 516);    // always 0 (force-bf16 flag)
  const void* zp = (const void*)(ws + 768);  // 16B+ zero page (memset below)
  int* cnt = (int*)(ws + 1024);        // M i32
  size_t o = aup(1024 + (size_t)M * 4);
  float* fin1 = (float*)(ws + o); o += 256;
  float* fin2 = (float*)(ws + o); o += 256;
  int* slots = (int*)(ws + o); o = aup(o + (size_t)M * 32);
  bf16* xd = (bf16*)(ws + o); o += (size_t)M * 256;
  bf16* hd = (bf16*)(ws + o); o += (size_t)M * 256;
  bf16* h1 = (bf16*)(ws + o); o += (size_t)M * 512;
  bf16* wt1 = (bf16*)(ws + o); o += (size_t)27 * 256 * 128 * 2;
  bf16* wt2 = (bf16*)(ws + o); o += ((size_t)27 * 256 * 256 + 256 * 128) * 2;
  (void)ws_size; (void)n_in;

  // zero stats + flags + zero-page + counts (ws is poisoned before every call)
  hipMemsetAsync(ws, 0, 1024 + (size_t)M * 4, stream);

  // dtype detection (writes flag)
  detect_k<<<1, 64, 0, stream>>>(gn1w, flag);

  // weight transposes: W[k][ci][co] -> Wt[k][co][ci]; Wskip appended to wt2
  transpose_k<<<dim3(4 * 8, 27), 256, 0, stream>>>(W1, wt1, 128, 256, flag);
  transpose_k<<<dim3(8 * 8, 27), 256, 0, stream>>>(W2, wt2, 256, 256, flag);
  transpose_k<<<dim3(4 * 8, 1), 256, 0, stream>>>(
      Wsk, wt2 + (size_t)27 * 256 * 256, 128, 256, flag);

  // GN1 stats over all N voxels
  gn_stats_k<<<512, 256, 0, stream>>>(feats, raw1, N, 128, flag);
  gn_fin_k<<<1, 64, 0, stream>>>(raw1, fin1, (float)N * 4.f);

  // downsample structure + gather
  slots_k<<<(N + 255) / 256, 256, 0, stream>>>(pool, cnt, slots, N);
  down_k<<<(M + 1) / 2, 256, 0, stream>>>(feats, slots, cnt, fin1, gn1w, gn1b,
                                          xd, hd, M, flag);

  const int nby = (M + 127) / 128;
  const int nwg = 2 * nby;

  // conv1: h1 = gatherGEMM(hd, W1) + b1   (h1 is bf16 -> outflag = zeroflag)
  conv_k<128, false><<<nwg, 256, 0, stream>>>(
      hd, wt1, b1, nullptr, nullptr, nbr, h1, M, nwg, zp, flag, zeroflag);

  // GN2 + SiLU (in place on h1; h1 is bf16 -> force-bf16 flag for stats)
  gn_stats_k<<<512, 256, 0, stream>>>(h1, raw2, M, 256, zeroflag);
  gn_fin_k<<<1, 64, 0, stream>>>(raw2, fin2, (float)M * 8.f);
  act2_k<<<(int)(((size_t)M * 32 + 255) / 256), 256, 0, stream>>>(
      h1, fin2, gn2w, gn2b, (size_t)M * 32, flag);

  // conv2 + fused skip (28th "neighbor" = self over xd with Wskip^T) + b2+bskip
  conv_k<256, true><<<nwg, 256, 0, stream>>>(
      h1, wt2, b2, bsk, xd, nbr, d_out, M, nwg, zp, flag, flag);
}

// Round 2
// 1479.339 us; speedup vs baseline: 1.0419x; 1.0096x over previous
//
#include <hip/hip_runtime.h>
#include <hip/hip_bf16.h>
#include <stdint.h>

typedef __hip_bfloat16 bf16;
typedef __attribute__((ext_vector_type(8))) __bf16 bf16x8;
typedef __attribute__((ext_vector_type(4))) float f32x4;

#define GN_EPS 1e-5f

__device__ __forceinline__ float silu_f(float x) {
  return x / (1.f + __expf(-x));
}

// dtype-dual scalar load: flag==1 -> f32 data, flag==0 -> bf16 data
__device__ __forceinline__ float ldf(const void* p, size_t i, int f) {
  return f ? ((const float*)p)[i]
           : __bfloat162float(((const bf16*)p)[i]);
}

// async global->LDS, 16B per lane. LDS dest is wave-uniform base (+lane*16 HW).
__device__ __forceinline__ void llds16(const void* g, void* l) {
  __builtin_amdgcn_global_load_lds(
      (const __attribute__((address_space(1))) unsigned int*)g,
      (__attribute__((address_space(3))) unsigned int*)l, 16, 0, 0);
}

// ---------------- dtype detect: scan gn1_w as bf16 halves -------------------
__global__ void detect_k(const void* __restrict__ gn1w, int* __restrict__ flag) {
  if (threadIdx.x == 0 && blockIdx.x == 0) {
    const unsigned short* u = (const unsigned short*)gn1w;
    float mx = 0.f;
    for (int i = 0; i < 128; ++i) {
      unsigned int b = ((unsigned int)u[i]) << 16;
      float v = __uint_as_float(b);
      v = fabsf(v);
      if (!isnan(v) && v > mx) mx = v;
    }
    flag[0] = (mx > 1e4f) ? 1 : 0;
  }
}

// ---------------- transpose (K, CI, CO) -> (K, CO, CI), out bf16 ------------
__global__ void transpose_k(const void* __restrict__ in, bf16* __restrict__ out,
                            int CI, int CO, const int* __restrict__ flagp) {
  const int f = *flagp;
  int k = blockIdx.y;
  int ntco = CO >> 5;
  int tci = blockIdx.x / ntco, tco = blockIdx.x % ntco;
  __shared__ float t[32][33];
  int tx = threadIdx.x & 31, ty = threadIdx.x >> 5;
  size_t base = (size_t)k * CI * CO;
  bf16* dst = out + base;
#pragma unroll
  for (int j = 0; j < 4; ++j)
    t[ty + 8 * j][tx] =
        ldf(in, base + (size_t)(tci * 32 + ty + 8 * j) * CO + tco * 32 + tx, f);
  __syncthreads();
#pragma unroll
  for (int j = 0; j < 4; ++j)
    dst[(size_t)(tco * 32 + ty + 8 * j) * CI + tci * 32 + tx] =
        __float2bfloat16(t[tx][ty + 8 * j]);
}

// ---------------- group-norm stats: sum/sumsq per group ----
__global__ void gn_stats_k(const void* __restrict__ x, float* __restrict__ raw,
                           int rows, int C, const int* __restrict__ flagp) {
  const int f = *flagp;
  int tid = threadIdx.x;
  int rpb = 256 / C;
  int c = tid & (C - 1);
  int stripe = tid / C;
  float s = 0.f, sq = 0.f;
  for (int r = blockIdx.x * rpb + stripe; r < rows; r += gridDim.x * rpb) {
    float v = ldf(x, (size_t)r * C + c, f);
    s += v; sq += v * v;
  }
  __shared__ float ls[256], lq[256];
  ls[tid] = s; lq[tid] = sq;
  __syncthreads();
  if (tid < 32) {
    int per = C >> 5;
    float as = 0.f, aq = 0.f;
    for (int st = 0; st < rpb; ++st)
      for (int e = 0; e < per; ++e) {
        int idx = st * C + tid * per + e;
        as += ls[idx]; aq += lq[idx];
      }
    atomicAdd(&raw[tid], as);
    atomicAdd(&raw[32 + tid], aq);
  }
}

__global__ void gn_fin_k(const float* __restrict__ raw, float* __restrict__ fin,
                         float count) {
  int g = threadIdx.x;
  if (g < 32) {
    float mu = raw[g] / count;
    float var = fmaxf(raw[32 + g] / count - mu * mu, 0.f);
    fin[g] = mu;
    fin[32 + g] = rsqrtf(var + GN_EPS);
  }
}

// ---------------- build per-cell voxel slots (<=8 parents per 2x cell) ------
__global__ void slots_k(const int* __restrict__ seg, int* __restrict__ cnt,
                        int* __restrict__ slots, int N) {
  int i = blockIdx.x * 256 + threadIdx.x;
  if (i >= N) return;
  int s = seg[i];
  int p = atomicAdd(&cnt[s], 1);
  if (p < 8) slots[s * 8 + p] = i;
}

// ---------------- downsample: x_d = mean(f), h_d = mean(silu(gn1(f))) -------
__global__ void down_k(const void* __restrict__ feats, const int* __restrict__ slots,
                       const int* __restrict__ cnt, const float* __restrict__ fin1,
                       const void* __restrict__ gw, const void* __restrict__ gb,
                       bf16* __restrict__ xd, bf16* __restrict__ hd, int M,
                       const int* __restrict__ flagp) {
  const int f = *flagp;
  int cell = blockIdx.x * 2 + (threadIdx.x >> 7);
  int c = threadIdx.x & 127;
  if (cell >= M) return;
  int n = min(cnt[cell], 8);
  int g = c >> 2;
  float mu = fin1[g], is = fin1[32 + g];
  float w = ldf(gw, c, f), b = ldf(gb, c, f);
  float xs = 0.f, hs = 0.f;
  for (int j = 0; j < n; ++j) {
    int v = slots[cell * 8 + j];
    float fv = ldf(feats, (size_t)v * 128 + c, f);
    xs += fv;
    hs += silu_f((fv - mu) * is * w + b);
  }
  float inv = 1.f / (float)max(n, 1);
  xd[(size_t)cell * 128 + c] = __float2bfloat16(xs * inv);
  hd[(size_t)cell * 128 + c] = __float2bfloat16(hs * inv);
}

// ---------------- h2 = silu(gn2(h1)) in-place, vectorized bf16x8 ------------
__global__ void act2_k(bf16* __restrict__ h, const float* __restrict__ fin2,
                       const void* __restrict__ gw, const void* __restrict__ gb,
                       size_t total8, const int* __restrict__ flagp) {
  const int f = *flagp;
  size_t i = (size_t)blockIdx.x * 256 + threadIdx.x;
  if (i >= total8) return;
  int c0 = (int)((i * 8) & 255);       // 8 consecutive channels, same group
  int g = c0 >> 3;
  float mu = fin2[g], is = fin2[32 + g];
  bf16x8 v = *reinterpret_cast<bf16x8*>(h + i * 8);
  bf16x8 o;
#pragma unroll
  for (int j = 0; j < 8; ++j) {
    float x = (float)v[j];
    float t = (x - mu) * is * ldf(gw, c0 + j, f) + ldf(gb, c0 + j, f);
    o[j] = (__bf16)silu_f(t);
  }
  *reinterpret_cast<bf16x8*>(h + i * 8) = o;
}

// ---------------- gather-GEMM conv, v3 ---------------------------------------
// BM=192 x BN=256 tile, 512 threads (8 waves as 2x4, each 96x64 output).
// BK=32 slabs, ring-of-4 LDS buffers, counted vmcnt (3 slabs in flight across
// raw s_barriers -- T3/T4), nbr table staged in LDS so the steady-state loop
// issues ONLY global_load_lds (exact vmcnt ledger). 64B LDS rows with chunk
// swizzle c^((row>>1)&3): frag ds_read_b128 hits 64 distinct 16B slots
// (conflict-free); staging pre-swizzles the global source (m173).
// Wt layout: [k][cout][cin]; if SKIP, 28th block at Wt + 27*256*CIN with
// layout [cout][128] fed by Xd (src = self). Missing neighbors -> zero page.
template <int CIN, bool SKIP>
__global__ __launch_bounds__(512, 2) void conv_k(
    const bf16* __restrict__ A, const bf16* __restrict__ Wt,
    const void* __restrict__ bias, const void* __restrict__ bias2,
    const bf16* __restrict__ Xd, const int* __restrict__ nbr,
    void* __restrict__ out, int M, int nwg, const void* __restrict__ zp,
    const int* __restrict__ biasflagp, const int* __restrict__ outflagp) {
  constexpr int NCB = CIN / 32;                  // slabs per neighbor
  constexpr int LOG_NCB = (CIN == 256) ? 3 : 2;
  constexpr int NT = 27 * NCB + (SKIP ? 4 : 0);  // total slabs
  // LDS: A-ring 4x12KB | B-ring 4x16KB | nbrT 27x256 ints = 142336 B
  __shared__ alignas(16) char smem[49152 + 65536 + 27648];
  char* Aring = smem;
  char* Bring = smem + 49152;
  int* nbrT = (int*)(smem + 49152 + 65536);

  const int bflag = *biasflagp, oflag = *outflagp;
  const int tid = threadIdx.x;
  const int wave = tid >> 6, lane = tid & 63;

  // --- XCD-aware bijective block swizzle (m204) ---
  int bid = blockIdx.x;
  int q = nwg >> 3, r8 = nwg & 7, xcd = bid & 7, ix = bid >> 3;
  int wg = (xcd < r8 ? xcd * (q + 1) : r8 * (q + 1) + (xcd - r8) * q) + ix;
  const int row0 = wg * 192;

  // ---- fill nbr table: nbrT[k*256 + r] = nbr[(row0+r)*27 + k] (or -1) ------
  for (int i = tid; i < 27 * 256; i += 512) {
    int k = i >> 8, r = i & 255;
    int g = row0 + r;
    int v = -1;
    if (r < 192 && g < M) v = nbr[(size_t)g * 27 + k];
    nbrT[i] = v;
  }
  __syncthreads();

  // staging geometry: 16-row panel per issue; lane -> (row=l>>2, chunk=l&3)
  const int srow = lane >> 2;
  const int schk = lane & 3;

  auto stage = [&](int t) {
    char* Asl = Aring + (size_t)(t & 3) * 12288;
    char* Bsl = Bring + (size_t)(t & 3) * 16384;
    const bool isW = (!SKIP) || (t < 27 * NCB);
    const int kk = t >> LOG_NCB;                 // valid only when isW
    const int cb = isW ? (t & (NCB - 1)) : (t - 27 * NCB);
    const int cink = isW ? CIN : 128;
    const bf16* Ab = isW ? A : Xd;
    const bf16* Wb = Wt + (isW ? (size_t)kk * (256 * CIN)
                               : (size_t)27 * (256 * CIN));
    const int koff = cb * 32;
    // B: 2 panels (all waves)
#pragma unroll
    for (int ro = 0; ro < 2; ++ro) {
      int c = ro * 128 + wave * 16 + srow;
      int lc = schk ^ ((c >> 1) & 3);
      llds16(Wb + (size_t)c * cink + koff + lc * 8,
             Bsl + (size_t)(ro * 128 + wave * 16) * 64);
    }
    // A panel 0 (all waves): rows wave*16 .. +15
    {
      int r = wave * 16 + srow;
      int src;
      if (isW) src = nbrT[(kk << 8) + r];
      else { int g = row0 + r; src = (g < M) ? g : -1; }
      int lc = schk ^ ((r >> 1) & 3);
      const bf16* ga = (src >= 0) ? Ab + (size_t)src * cink + koff + lc * 8
                                  : (const bf16*)zp;
      llds16(ga, Asl + (size_t)(wave * 16) * 64);
    }
    // A panel 1 (waves 0..3 only): rows 128 + wave*16 .. +15
    if (wave < 4) {
      int r = 128 + wave * 16 + srow;
      int src;
      if (isW) src = nbrT[(kk << 8) + r];
      else { int g = row0 + r; src = (g < M) ? g : -1; }
      int lc = schk ^ ((r >> 1) & 3);
      const bf16* ga = (src >= 0) ? Ab + (size_t)src * cink + koff + lc * 8
                                  : (const bf16*)zp;
      llds16(ga, Asl + (size_t)(128 + wave * 16) * 64);
    }
  };
  // per-wave loads per slab: waves 0..3 -> 4, waves 4..7 -> 3

  // fragment geometry
  const int mrow = lane & 15, quad = lane >> 4;
  const int wr = wave >> 2, wc = wave & 3;       // 2 x 4 wave grid
  const int cswz = (quad ^ ((mrow >> 1) & 3)) * 16;

  f32x4 acc[6][4] = {};

  auto compute = [&](int t) {
    const char* As = Aring + (size_t)(t & 3) * 12288 +
                     (size_t)(wr * 96 + mrow) * 64 + cswz;
    const char* Bs = Bring + (size_t)(t & 3) * 16384 +
                     (size_t)(wc * 64 + mrow) * 64 + cswz;
    bf16x8 af[6], bv[4];
#pragma unroll
    for (int i = 0; i < 6; ++i)
      af[i] = *reinterpret_cast<const bf16x8*>(As + i * (16 * 64));
#pragma unroll
    for (int j = 0; j < 4; ++j)
      bv[j] = *reinterpret_cast<const bf16x8*>(Bs + j * (16 * 64));
    __builtin_amdgcn_s_setprio(1);
#pragma unroll
    for (int i = 0; i < 6; ++i)
#pragma unroll
      for (int j = 0; j < 4; ++j)
        acc[i][j] = __builtin_amdgcn_mfma_f32_16x16x32_bf16(af[i], bv[j],
                                                            acc[i][j], 0, 0, 0);
    __builtin_amdgcn_s_setprio(0);
  };

#define VMW(a, b)                                                      \
  do {                                                                 \
    if (wave < 4) asm volatile("s_waitcnt vmcnt(" #a ")" ::: "memory"); \
    else          asm volatile("s_waitcnt vmcnt(" #b ")" ::: "memory"); \
  } while (0)
#define BAR() asm volatile("s_barrier" ::: "memory")

  // prologue: 3 slabs in flight
  stage(0); stage(1); stage(2);

#pragma unroll 1
  for (int t = 0; t < NT - 3; ++t) {
    stage(t + 3);          // issue next slab (never waited to 0 in loop)
    VMW(12, 9);            // slab t's loads complete; t+1..t+3 stay in flight
    BAR();
    compute(t);
    BAR();                 // all waves done reading before buf reuse
  }
  VMW(8, 6); BAR(); compute(NT - 3); BAR();
  VMW(4, 3); BAR(); compute(NT - 2); BAR();
  VMW(0, 0); BAR(); compute(NT - 1);

#undef VMW
#undef BAR

  // ---- epilogue: bias (+bias2), store. C/D: col=lane&15, row=quad*4+r ------
#pragma unroll
  for (int j = 0; j < 4; ++j) {
    int col = wc * 64 + j * 16 + mrow;
    float bvl = ldf(bias, col, bflag);
    if (SKIP) bvl += ldf(bias2, col, bflag);
#pragma unroll
    for (int i = 0; i < 6; ++i) {
      int rb = row0 + wr * 96 + i * 16 + quad * 4;
#pragma unroll
      for (int r = 0; r < 4; ++r) {
        int row = rb + r;
        if (row < M) {
          size_t idx = (size_t)row * 256 + col;
          float val = acc[i][j][r] + bvl;
          if (oflag) ((float*)out)[idx] = val;
          else ((bf16*)out)[idx] = __float2bfloat16(val);
        }
      }
    }
  }
}

extern "C" void kernel_launch(void* const* d_in, const int* in_sizes, int n_in,
                              void* d_out, int out_size, void* d_ws, size_t ws_size,
                              hipStream_t stream) {
  const void* feats = d_in[0];
  const void* gn1w = d_in[1];
  const void* gn1b = d_in[2];
  const void* W1 = d_in[3];
  const void* b1 = d_in[4];
  const void* gn2w = d_in[5];
  const void* gn2b = d_in[6];
  const void* W2 = d_in[7];
  const void* b2 = d_in[8];
  const void* Wsk = d_in[9];
  const void* bsk = d_in[10];
  const int* pool = (const int*)d_in[11];
  const int* nbr = (const int*)d_in[12];
  const int N = in_sizes[0] / 128;
  const int M = out_size / 256;

  char* ws = (char*)d_ws;
  auto aup = [](size_t x) { return (x + 255) & ~(size_t)255; };
  float* raw1 = (float*)(ws + 0);      // 64 f32
  float* raw2 = (float*)(ws + 256);    // 64 f32
  int* flag = (int*)(ws + 512);        // dtype flag (1 = f32 inputs)
  int* zeroflag = (int*)(ws + 516);    // always 0 (force-bf16 flag)
  const void* zp = (const void*)(ws + 768);  // 16B+ zero page (memset below)
  int* cnt = (int*)(ws + 1024);        // M i32
  size_t o = aup(1024 + (size_t)M * 4);
  float* fin1 = (float*)(ws + o); o += 256;
  float* fin2 = (float*)(ws + o); o += 256;
  int* slots = (int*)(ws + o); o = aup(o + (size_t)M * 32);
  bf16* xd = (bf16*)(ws + o); o += (size_t)M * 256;
  bf16* hd = (bf16*)(ws + o); o += (size_t)M * 256;
  bf16* h1 = (bf16*)(ws + o); o += (size_t)M * 512;
  bf16* wt1 = (bf16*)(ws + o); o += (size_t)27 * 256 * 128 * 2;
  bf16* wt2 = (bf16*)(ws + o); o += ((size_t)27 * 256 * 256 + 256 * 128) * 2;
  (void)ws_size; (void)n_in;

  // zero stats + flags + zero-page + counts (ws is poisoned before every call)
  hipMemsetAsync(ws, 0, 1024 + (size_t)M * 4, stream);

  // dtype detection (writes flag)
  detect_k<<<1, 64, 0, stream>>>(gn1w, flag);

  // weight transposes: W[k][ci][co] -> Wt[k][co][ci]; Wskip appended to wt2
  transpose_k<<<dim3(4 * 8, 27), 256, 0, stream>>>(W1, wt1, 128, 256, flag);
  transpose_k<<<dim3(8 * 8, 27), 256, 0, stream>>>(W2, wt2, 256, 256, flag);
  transpose_k<<<dim3(4 * 8, 1), 256, 0, stream>>>(
      Wsk, wt2 + (size_t)27 * 256 * 256, 128, 256, flag);

  // GN1 stats over all N voxels
  gn_stats_k<<<512, 256, 0, stream>>>(feats, raw1, N, 128, flag);
  gn_fin_k<<<1, 64, 0, stream>>>(raw1, fin1, (float)N * 4.f);

  // downsample structure + gather
  slots_k<<<(N + 255) / 256, 256, 0, stream>>>(pool, cnt, slots, N);
  down_k<<<(M + 1) / 2, 256, 0, stream>>>(feats, slots, cnt, fin1, gn1w, gn1b,
                                          xd, hd, M, flag);

  const int nwg = (M + 191) / 192;

  // conv1: h1 = gatherGEMM(hd, W1) + b1   (h1 is bf16 -> outflag = zeroflag)
  conv_k<128, false><<<nwg, 512, 0, stream>>>(
      hd, wt1, b1, nullptr, nullptr, nbr, h1, M, nwg, zp, flag, zeroflag);

  // GN2 + SiLU (in place on h1; h1 is bf16 -> force-bf16 flag for stats)
  gn_stats_k<<<512, 256, 0, stream>>>(h1, raw2, M, 256, zeroflag);
  gn_fin_k<<<1, 64, 0, stream>>>(raw2, fin2, (float)M * 8.f);
  act2_k<<<(int)(((size_t)M * 32 + 255) / 256), 256, 0, stream>>>(
      h1, fin2, gn2w, gn2b, (size_t)M * 32, flag);

  // conv2 + fused skip (28th "neighbor" = self over xd with Wskip^T) + b2+bskip
  conv_k<256, true><<<nwg, 512, 0, stream>>>(
      h1, wt2, b2, bsk, xd, nbr, d_out, M, nwg, zp, flag, flag);
}

// Round 3
// 1375.001 us; speedup vs baseline: 1.1209x; 1.0759x over previous
//
#include <hip/hip_runtime.h>
#include <hip/hip_bf16.h>
#include <stdint.h>

typedef __hip_bfloat16 bf16;
typedef __attribute__((ext_vector_type(8))) __bf16 bf16x8;
typedef __attribute__((ext_vector_type(4))) float f32x4;

#define GN_EPS 1e-5f

__device__ __forceinline__ float silu_f(float x) {
  return x / (1.f + __expf(-x));
}

// dtype-dual scalar load: flag==1 -> f32 data, flag==0 -> bf16 data
__device__ __forceinline__ float ldf(const void* p, size_t i, int f) {
  return f ? ((const float*)p)[i]
           : __bfloat162float(((const bf16*)p)[i]);
}

// async global->LDS, 16B per lane. LDS dest is wave-uniform base (+lane*16 HW).
__device__ __forceinline__ void llds16(const void* g, void* l) {
  __builtin_amdgcn_global_load_lds(
      (const __attribute__((address_space(1))) unsigned int*)g,
      (__attribute__((address_space(3))) unsigned int*)l, 16, 0, 0);
}

// direct global->VGPR 16B load, saddr + 32b voffset form (part of vmcnt ledger)
__device__ __forceinline__ void gload16(bf16x8& d, const bf16* base, int voff) {
  asm volatile("global_load_dwordx4 %0, %1, %2"
               : "=&v"(d) : "v"(voff), "s"(base) : "memory");
}

// ---------------- dtype detect: scan gn1_w as bf16 halves -------------------
__global__ void detect_k(const void* __restrict__ gn1w, int* __restrict__ flag) {
  if (threadIdx.x == 0 && blockIdx.x == 0) {
    const unsigned short* u = (const unsigned short*)gn1w;
    float mx = 0.f;
    for (int i = 0; i < 128; ++i) {
      unsigned int b = ((unsigned int)u[i]) << 16;
      float v = __uint_as_float(b);
      v = fabsf(v);
      if (!isnan(v) && v > mx) mx = v;
    }
    flag[0] = (mx > 1e4f) ? 1 : 0;
  }
}

// -------- transpose (K, CI, CO) -> chunked (K, CI/32, CO, 32), out bf16 -----
// Wf[k][cb][co][ci&31]: per-slab fragment loads are contiguous per 16-col group
__global__ void transpose_k(const void* __restrict__ in, bf16* __restrict__ out,
                            int CI, int CO, const int* __restrict__ flagp) {
  const int f = *flagp;
  int k = blockIdx.y;
  int ntco = CO >> 5;
  int tci = blockIdx.x / ntco, tco = blockIdx.x % ntco;
  __shared__ float t[32][33];
  int tx = threadIdx.x & 31, ty = threadIdx.x >> 5;
  size_t base = (size_t)k * CI * CO;
  bf16* dst = out + base;
#pragma unroll
  for (int j = 0; j < 4; ++j)
    t[ty + 8 * j][tx] =
        ldf(in, base + (size_t)(tci * 32 + ty + 8 * j) * CO + tco * 32 + tx, f);
  __syncthreads();
#pragma unroll
  for (int j = 0; j < 4; ++j)
    dst[(size_t)tci * (CO * 32) + (size_t)(tco * 32 + ty + 8 * j) * 32 + tx] =
        __float2bfloat16(t[tx][ty + 8 * j]);
}

// ---------------- group-norm stats: sum/sumsq per group ----
__global__ void gn_stats_k(const void* __restrict__ x, float* __restrict__ raw,
                           int rows, int C, const int* __restrict__ flagp) {
  const int f = *flagp;
  int tid = threadIdx.x;
  int rpb = 256 / C;
  int c = tid & (C - 1);
  int stripe = tid / C;
  float s = 0.f, sq = 0.f;
  for (int r = blockIdx.x * rpb + stripe; r < rows; r += gridDim.x * rpb) {
    float v = ldf(x, (size_t)r * C + c, f);
    s += v; sq += v * v;
  }
  __shared__ float ls[256], lq[256];
  ls[tid] = s; lq[tid] = sq;
  __syncthreads();
  if (tid < 32) {
    int per = C >> 5;
    float as = 0.f, aq = 0.f;
    for (int st = 0; st < rpb; ++st)
      for (int e = 0; e < per; ++e) {
        int idx = st * C + tid * per + e;
        as += ls[idx]; aq += lq[idx];
      }
    atomicAdd(&raw[tid], as);
    atomicAdd(&raw[32 + tid], aq);
  }
}

__global__ void gn_fin_k(const float* __restrict__ raw, float* __restrict__ fin,
                         float count) {
  int g = threadIdx.x;
  if (g < 32) {
    float mu = raw[g] / count;
    float var = fmaxf(raw[32 + g] / count - mu * mu, 0.f);
    fin[g] = mu;
    fin[32 + g] = rsqrtf(var + GN_EPS);
  }
}

// ---------------- build per-cell voxel slots (<=8 parents per 2x cell) ------
__global__ void slots_k(const int* __restrict__ seg, int* __restrict__ cnt,
                        int* __restrict__ slots, int N) {
  int i = blockIdx.x * 256 + threadIdx.x;
  if (i >= N) return;
  int s = seg[i];
  int p = atomicAdd(&cnt[s], 1);
  if (p < 8) slots[s * 8 + p] = i;
}

// ---------------- downsample: x_d = mean(f), h_d = mean(silu(gn1(f))) -------
__global__ void down_k(const void* __restrict__ feats, const int* __restrict__ slots,
                       const int* __restrict__ cnt, const float* __restrict__ fin1,
                       const void* __restrict__ gw, const void* __restrict__ gb,
                       bf16* __restrict__ xd, bf16* __restrict__ hd, int M,
                       const int* __restrict__ flagp) {
  const int f = *flagp;
  int cell = blockIdx.x * 2 + (threadIdx.x >> 7);
  int c = threadIdx.x & 127;
  if (cell >= M) return;
  int n = min(cnt[cell], 8);
  int g = c >> 2;
  float mu = fin1[g], is = fin1[32 + g];
  float w = ldf(gw, c, f), b = ldf(gb, c, f);
  float xs = 0.f, hs = 0.f;
  for (int j = 0; j < n; ++j) {
    int v = slots[cell * 8 + j];
    float fv = ldf(feats, (size_t)v * 128 + c, f);
    xs += fv;
    hs += silu_f((fv - mu) * is * w + b);
  }
  float inv = 1.f / (float)max(n, 1);
  xd[(size_t)cell * 128 + c] = __float2bfloat16(xs * inv);
  hd[(size_t)cell * 128 + c] = __float2bfloat16(hs * inv);
}

// ---------------- h2 = silu(gn2(h1)) in-place, vectorized bf16x8 ------------
__global__ void act2_k(bf16* __restrict__ h, const float* __restrict__ fin2,
                       const void* __restrict__ gw, const void* __restrict__ gb,
                       size_t total8, const int* __restrict__ flagp) {
  const int f = *flagp;
  size_t i = (size_t)blockIdx.x * 256 + threadIdx.x;
  if (i >= total8) return;
  int c0 = (int)((i * 8) & 255);       // 8 consecutive channels, same group
  int g = c0 >> 3;
  float mu = fin2[g], is = fin2[32 + g];
  bf16x8 v = *reinterpret_cast<bf16x8*>(h + i * 8);
  bf16x8 o;
#pragma unroll
  for (int j = 0; j < 8; ++j) {
    float x = (float)v[j];
    float t = (x - mu) * is * ldf(gw, c0 + j, f) + ldf(gb, c0 + j, f);
    o[j] = (__bf16)silu_f(t);
  }
  *reinterpret_cast<bf16x8*>(h + i * 8) = o;
}

// ---------------- gather-GEMM conv, v4 ---------------------------------------
// BM=192 x BN=256, 512 threads (8 waves 2x4, wave tile 96x64). BK=32 slabs.
// A (gathered activations): LDS ring-4 via global_load_lds, chunk-swizzled.
// B (weights): DIRECT global->register fragments (chunked Wf layout), double-
// buffered, asm loads inside an exact vmcnt ledger. LDS traffic/slab drops
// 28KB-write/80KB-read -> 12/48, making the MFMA pipe the critical resource.
// 1 barrier per slab. Counted vmcnt never drains to 0 in steady state (T4).
template <int CIN, bool SKIP>
__global__ __launch_bounds__(512, 2) void conv_k(
    const bf16* __restrict__ A, const bf16* __restrict__ Wt,
    const void* __restrict__ bias, const void* __restrict__ bias2,
    const bf16* __restrict__ Xd, const int* __restrict__ nbr,
    void* __restrict__ out, int M, int nwg, const void* __restrict__ zp,
    const int* __restrict__ biasflagp, const int* __restrict__ outflagp) {
  constexpr int NCB = CIN / 32;                  // slabs per neighbor tap
  constexpr int LOG_NCB = (CIN == 256) ? 3 : 2;
  constexpr int NT = 27 * NCB + (SKIP ? 4 : 0);  // total slabs (even)
  // LDS: A-ring 4x12KB | nbrT 27x256 ints = 76800 B
  __shared__ alignas(16) char smem[49152 + 27648];
  char* Aring = smem;
  int* nbrT = (int*)(smem + 49152);

  const int bflag = *biasflagp, oflag = *outflagp;
  const int tid = threadIdx.x;
  const int wave = tid >> 6, lane = tid & 63;
  const bool w03 = (wave < 4);

  // --- XCD-aware bijective block swizzle (m204) ---
  int bid = blockIdx.x;
  int q = nwg >> 3, r8 = nwg & 7, xcd = bid & 7, ix = bid >> 3;
  int wg = (xcd < r8 ? xcd * (q + 1) : r8 * (q + 1) + (xcd - r8) * q) + ix;
  const int row0 = wg * 192;

  // ---- fill nbr table: nbrT[k*256 + r] = nbr[(row0+r)*27 + k] (or -1) ------
  for (int i = tid; i < 27 * 256; i += 512) {
    int k = i >> 8, r = i & 255;
    int g = row0 + r;
    int v = -1;
    if (r < 192 && g < M) v = nbr[(size_t)g * 27 + k];
    nbrT[i] = v;
  }
  __syncthreads();

  // staging: panel = 16 rows x 64B = one llds (lane -> row l>>2, chunk l&3)
  // waves 0-3: panels {2w, 2w+1}; waves 4-7: panel {4+w}. nA = 2 / 1.
  const int srow = lane >> 2;
  const int schk = lane & 3;

  auto stageA1 = [&](int t, int panel, char* Asl, bool isW, int kk, int koff,
                     int cink, const bf16* Ab) {
    int r = panel * 16 + srow;
    int src;
    if (isW) src = nbrT[(kk << 8) + r];
    else { int g = row0 + r; src = (g < M) ? g : -1; }
    int lc = schk ^ ((r >> 1) & 3);
    const bf16* ga = (src >= 0) ? Ab + (size_t)src * cink + koff + lc * 8
                                : (const bf16*)zp;
    llds16(ga, Asl + (size_t)panel * 1024);
  };

  auto stageA = [&](int t) {
    char* Asl = Aring + (size_t)(t & 3) * 12288;
    const bool isW = (!SKIP) || (t < 27 * NCB);
    const int kk = t >> LOG_NCB;
    const int cb = isW ? (t & (NCB - 1)) : (t - 27 * NCB);
    const int cink = isW ? CIN : 128;
    const bf16* Ab = isW ? A : Xd;
    const int koff = cb * 32;
    if (w03) {
      stageA1(t, 2 * wave, Asl, isW, kk, koff, cink, Ab);
      stageA1(t, 2 * wave + 1, Asl, isW, kk, koff, cink, Ab);
    } else {
      stageA1(t, 4 + wave, Asl, isW, kk, koff, cink, Ab);
    }
  };

  // fragment geometry
  const int mrow = lane & 15, quad = lane >> 4;
  const int wr = wave >> 2, wc = wave & 3;       // 2 x 4 wave grid
  const int cswz = (quad ^ ((mrow >> 1) & 3)) * 16;

  // B fragment byte offsets (loop-invariant)
  int bvoff[4];
#pragma unroll
  for (int j = 0; j < 4; ++j)
    bvoff[j] = ((wc * 64 + j * 16 + mrow) * 32 + quad * 8) * 2;

  auto loadB = [&](bf16x8 (&dst)[4], int t) {
    const bool isW = (!SKIP) || (t < 27 * NCB);
    const int kk = t >> LOG_NCB;
    const int cb = isW ? (t & (NCB - 1)) : (t - 27 * NCB);
    const bf16* base = Wt +
        (isW ? (size_t)kk * (256 * CIN) : (size_t)27 * (256 * CIN)) +
        (size_t)cb * (256 * 32);
#pragma unroll
    for (int j = 0; j < 4; ++j) gload16(dst[j], base, bvoff[j]);
  };

  f32x4 acc[6][4] = {};

  auto compute = [&](int t, const bf16x8 (&bv)[4]) {
    const char* As = Aring + (size_t)(t & 3) * 12288 +
                     (size_t)(wr * 96 + mrow) * 64 + cswz;
    bf16x8 af[6];
#pragma unroll
    for (int i = 0; i < 6; ++i)
      af[i] = *reinterpret_cast<const bf16x8*>(As + i * (16 * 64));
    __builtin_amdgcn_s_setprio(1);
#pragma unroll
    for (int i = 0; i < 6; ++i)
#pragma unroll
      for (int j = 0; j < 4; ++j)
        acc[i][j] = __builtin_amdgcn_mfma_f32_16x16x32_bf16(af[i], bv[j],
                                                            acc[i][j], 0, 0, 0);
    __builtin_amdgcn_s_setprio(0);
  };

#define VMW(a, b)                                                        \
  do {                                                                   \
    if (w03) asm volatile("s_waitcnt vmcnt(" #a ")" ::: "memory");       \
    else     asm volatile("s_waitcnt vmcnt(" #b ")" ::: "memory");       \
    __builtin_amdgcn_sched_barrier(0);                                   \
  } while (0)
#define BAR() __builtin_amdgcn_s_barrier()

  bf16x8 bX[4], bY[4];

  // prologue
  stageA(0); stageA(1);
  loadB(bX, 0);

#pragma unroll 1
  for (int u = 0; u < NT / 2 - 1; ++u) {
    const int s = 2 * u;
    loadB(bY, s + 1);
    stageA(s + 2);
    VMW(6, 5);           // force A(s),A(s+1),B(s); keep A(s+2),B(s+1) in flight
    BAR();
    compute(s, bX);
    loadB(bX, s + 2);
    stageA(s + 3);
    VMW(8, 6);           // force B(s+1); keep A(s+2),A(s+3),B(s+2) in flight
    BAR();
    compute(s + 1, bY);
  }
  // tail: s = NT-2
  loadB(bY, NT - 1);
  VMW(6, 5);
  BAR();
  compute(NT - 2, bX);
  VMW(0, 0);
  BAR();
  compute(NT - 1, bY);

#undef VMW
#undef BAR

  // ---- epilogue: bias (+bias2), store. C/D: col=lane&15, row=quad*4+r ------
#pragma unroll
  for (int j = 0; j < 4; ++j) {
    int col = wc * 64 + j * 16 + mrow;
    float bvl = ldf(bias, col, bflag);
    if (SKIP) bvl += ldf(bias2, col, bflag);
#pragma unroll
    for (int i = 0; i < 6; ++i) {
      int rb = row0 + wr * 96 + i * 16 + quad * 4;
#pragma unroll
      for (int r = 0; r < 4; ++r) {
        int row = rb + r;
        if (row < M) {
          size_t idx = (size_t)row * 256 + col;
          float val = acc[i][j][r] + bvl;
          if (oflag) ((float*)out)[idx] = val;
          else ((bf16*)out)[idx] = __float2bfloat16(val);
        }
      }
    }
  }
}

extern "C" void kernel_launch(void* const* d_in, const int* in_sizes, int n_in,
                              void* d_out, int out_size, void* d_ws, size_t ws_size,
                              hipStream_t stream) {
  const void* feats = d_in[0];
  const void* gn1w = d_in[1];
  const void* gn1b = d_in[2];
  const void* W1 = d_in[3];
  const void* b1 = d_in[4];
  const void* gn2w = d_in[5];
  const void* gn2b = d_in[6];
  const void* W2 = d_in[7];
  const void* b2 = d_in[8];
  const void* Wsk = d_in[9];
  const void* bsk = d_in[10];
  const int* pool = (const int*)d_in[11];
  const int* nbr = (const int*)d_in[12];
  const int N = in_sizes[0] / 128;
  const int M = out_size / 256;

  char* ws = (char*)d_ws;
  auto aup = [](size_t x) { return (x + 255) & ~(size_t)255; };
  float* raw1 = (float*)(ws + 0);      // 64 f32
  float* raw2 = (float*)(ws + 256);    // 64 f32
  int* flag = (int*)(ws + 512);        // dtype flag (1 = f32 inputs)
  int* zeroflag = (int*)(ws + 516);    // always 0 (force-bf16 flag)
  const void* zp = (const void*)(ws + 768);  // zero page (memset below)
  int* cnt = (int*)(ws + 1024);        // M i32
  size_t o = aup(1024 + (size_t)M * 4);
  float* fin1 = (float*)(ws + o); o += 256;
  float* fin2 = (float*)(ws + o); o += 256;
  int* slots = (int*)(ws + o); o = aup(o + (size_t)M * 32);
  bf16* xd = (bf16*)(ws + o); o += (size_t)M * 256;
  bf16* hd = (bf16*)(ws + o); o += (size_t)M * 256;
  bf16* h1 = (bf16*)(ws + o); o += (size_t)M * 512;
  bf16* wt1 = (bf16*)(ws + o); o += (size_t)27 * 256 * 128 * 2;
  bf16* wt2 = (bf16*)(ws + o); o += ((size_t)27 * 256 * 256 + 256 * 128) * 2;
  (void)ws_size; (void)n_in;

  // zero stats + flags + zero-page + counts (ws is poisoned before every call)
  hipMemsetAsync(ws, 0, 1024 + (size_t)M * 4, stream);

  // dtype detection (writes flag)
  detect_k<<<1, 64, 0, stream>>>(gn1w, flag);

  // weight transposes -> chunked Wf[k][cb][co][32]; Wskip appended to wt2
  transpose_k<<<dim3(4 * 8, 27), 256, 0, stream>>>(W1, wt1, 128, 256, flag);
  transpose_k<<<dim3(8 * 8, 27), 256, 0, stream>>>(W2, wt2, 256, 256, flag);
  transpose_k<<<dim3(4 * 8, 1), 256, 0, stream>>>(
      Wsk, wt2 + (size_t)27 * 256 * 256, 128, 256, flag);

  // GN1 stats over all N voxels
  gn_stats_k<<<512, 256, 0, stream>>>(feats, raw1, N, 128, flag);
  gn_fin_k<<<1, 64, 0, stream>>>(raw1, fin1, (float)N * 4.f);

  // downsample structure + gather
  slots_k<<<(N + 255) / 256, 256, 0, stream>>>(pool, cnt, slots, N);
  down_k<<<(M + 1) / 2, 256, 0, stream>>>(feats, slots, cnt, fin1, gn1w, gn1b,
                                          xd, hd, M, flag);

  const int nwg = (M + 191) / 192;

  // conv1: h1 = gatherGEMM(hd, W1) + b1   (h1 is bf16 -> outflag = zeroflag)
  conv_k<128, false><<<nwg, 512, 0, stream>>>(
      hd, wt1, b1, nullptr, nullptr, nbr, h1, M, nwg, zp, flag, zeroflag);

  // GN2 + SiLU (in place on h1; h1 is bf16 -> force-bf16 flag for stats)
  gn_stats_k<<<512, 256, 0, stream>>>(h1, raw2, M, 256, zeroflag);
  gn_fin_k<<<1, 64, 0, stream>>>(raw2, fin2, (float)M * 8.f);
  act2_k<<<(int)(((size_t)M * 32 + 255) / 256), 256, 0, stream>>>(
      h1, fin2, gn2w, gn2b, (size_t)M * 32, flag);

  // conv2 + fused skip (28th "neighbor" = self over xd with Wskip^T) + b2+bskip
  conv_k<256, true><<<nwg, 512, 0, stream>>>(
      h1, wt2, b2, bsk, xd, nbr, d_out, M, nwg, zp, flag, flag);
}